// Round 6
// baseline (191.739 us; speedup 1.0000x reference)
//
#include <hip/hip_runtime.h>

// Problem constants (from reference)
#define B_    32
#define C_    256
#define H_    56
#define W_    56
#define HW    (H_ * W_)          // 3136
#define HW4   (HW / 4)           // 784 float4s per channel plane
#define NSEL  8
#define NTOT  (B_ * C_ * HW)     // 25,690,112 elements
#define NTOT4 (NTOT / 4)         // 6,422,528 float4s
#define NSELTOT4 (B_ * NSEL * HW4)  // 200,704 float4s in selected slice

#define RED_BLOCKS 256
#define RED_THREADS 256

// Native clang vector type: accepted by __builtin_nontemporal_store,
// same 16-byte layout/alignment as HIP float4.
typedef float f32x4 __attribute__((ext_vector_type(4)));

// ws layout (as float array):
// [0 .. RED_BLOCKS)                 partial mins
// [RED_BLOCKS .. 2*RED_BLOCKS)      partial maxes
// [2*RED_BLOCKS .. 2*RED_BLOCKS+5)  consts: mn, mx, sw0, sw1, sw2
// [2*RED_BLOCKS+8 ...)              int flags[256] (channel selected?)
#define WS_CONST (2 * RED_BLOCKS)
#define WS_FLAGS (2 * RED_BLOCKS + 8)

__global__ __launch_bounds__(RED_THREADS)
void k_minmax(const float* __restrict__ in, const int* __restrict__ sel,
              float* __restrict__ ws) {
    __shared__ float smn[RED_THREADS], smx[RED_THREADS];
    __shared__ int ssel[NSEL];
    if (threadIdx.x < NSEL) ssel[threadIdx.x] = sel[threadIdx.x];
    __syncthreads();

    float mn = INFINITY, mx = -INFINITY;
    const f32x4* in4 = reinterpret_cast<const f32x4*>(in);
    for (int i = blockIdx.x * blockDim.x + threadIdx.x; i < NSELTOT4;
         i += gridDim.x * blockDim.x) {
        int pos = i % HW4;
        int t   = i / HW4;
        int j   = t % NSEL;
        int b   = t / NSEL;
        int addr = (b * C_ + ssel[j]) * HW4 + pos;
        f32x4 v = in4[addr];
        mn = fminf(mn, fminf(fminf(v.x, v.y), fminf(v.z, v.w)));
        mx = fmaxf(mx, fmaxf(fmaxf(v.x, v.y), fmaxf(v.z, v.w)));
    }
    smn[threadIdx.x] = mn;
    smx[threadIdx.x] = mx;
    __syncthreads();
    for (int s = RED_THREADS / 2; s > 0; s >>= 1) {
        if (threadIdx.x < s) {
            smn[threadIdx.x] = fminf(smn[threadIdx.x], smn[threadIdx.x + s]);
            smx[threadIdx.x] = fmaxf(smx[threadIdx.x], smx[threadIdx.x + s]);
        }
        __syncthreads();
    }
    if (threadIdx.x == 0) {
        ws[blockIdx.x] = smn[0];
        ws[RED_BLOCKS + blockIdx.x] = smx[0];
    }
}

__global__ __launch_bounds__(RED_BLOCKS)
void k_finish(const float* __restrict__ beta, const int* __restrict__ sel,
              float* __restrict__ ws, float* __restrict__ out_scale) {
    __shared__ float smn[RED_BLOCKS], smx[RED_BLOCKS];
    int t = threadIdx.x;
    smn[t] = ws[t];
    smx[t] = ws[RED_BLOCKS + t];
    __syncthreads();
    for (int s = RED_BLOCKS / 2; s > 0; s >>= 1) {
        if (t < s) {
            smn[t] = fminf(smn[t], smn[t + s]);
            smx[t] = fmaxf(smx[t], smx[t + s]);
        }
        __syncthreads();
    }
    // channel-selected flags (one thread per channel, C_ == blockDim.x)
    int f = 0;
    #pragma unroll
    for (int j = 0; j < NSEL; ++j) f |= (sel[j] == t) ? 1 : 0;
    reinterpret_cast<int*>(ws + WS_FLAGS)[t] = f;

    if (t == 0) {
        float mn = smn[0], mx = smx[0];
        float b0 = beta[0], b1 = beta[1], b2 = beta[2];
        float m = fmaxf(b0, fmaxf(b1, b2));
        float e0 = expf(b0 - m), e1 = expf(b1 - m), e2 = expf(b2 - m);
        float inv = 1.0f / (e0 + e1 + e2);
        float* c = ws + WS_CONST;
        c[0] = mn;
        c[1] = mx;
        c[2] = e0 * inv;
        c[3] = e1 * inv;
        c[4] = e2 * inv;
        // returned scale is the last one (bit=8)
        out_scale[0] = (mx - mn) / 255.0f;
    }
}

__device__ __forceinline__ float qmix(float x, float mn,
                                      float sc2, float sc4, float sc8,
                                      float sw0, float sw1, float sw2) {
    float d = x - mn;
    // jnp.round == round-half-to-even == rintf (default rounding mode)
    float q2 = fminf(fmaxf(rintf(d / sc2), 0.0f), 3.0f);
    float q4 = fminf(fmaxf(rintf(d / sc4), 0.0f), 15.0f);
    float q8 = fminf(fmaxf(rintf(d / sc8), 0.0f), 255.0f);
    float o2 = q2 * sc2 + mn;
    float o4 = q4 * sc4 + mn;
    float o8 = q8 * sc8 + mn;
    return o2 * sw0 + o4 * sw1 + o8 * sw2;  // same left-to-right order as ref
}

__global__ __launch_bounds__(256)
void k_main(const float* __restrict__ in, float* __restrict__ out,
            const float* __restrict__ ws) {
    const float mn  = ws[WS_CONST + 0];
    const float mx  = ws[WS_CONST + 1];
    const float sw0 = ws[WS_CONST + 2];
    const float sw1 = ws[WS_CONST + 3];
    const float sw2 = ws[WS_CONST + 4];
    const int* flags = reinterpret_cast<const int*>(ws + WS_FLAGS);
    const float range = mx - mn;
    const float sc2 = range / 3.0f;
    const float sc4 = range / 15.0f;
    const float sc8 = range / 255.0f;

    const f32x4* in4 = reinterpret_cast<const f32x4*>(in);
    f32x4* out4 = reinterpret_cast<f32x4*>(out);

    for (int i = blockIdx.x * blockDim.x + threadIdx.x; i < NTOT4;
         i += gridDim.x * blockDim.x) {
        f32x4 v = in4[i];
        int c = (i / HW4) % C_;  // float4 is fully inside one channel plane
        if (flags[c]) {
            v.x = qmix(v.x, mn, sc2, sc4, sc8, sw0, sw1, sw2);
            v.y = qmix(v.y, mn, sc2, sc4, sc8, sw0, sw1, sw2);
            v.z = qmix(v.z, mn, sc2, sc4, sc8, sw0, sw1, sw2);
            v.w = qmix(v.w, mn, sc2, sc4, sc8, sw0, sw1, sw2);
        }
        // Streaming write, no reuse: non-temporal hint keeps the 100 MB
        // write stream from evicting cache lines (coherent, safe).
        __builtin_nontemporal_store(v, &out4[i]);
    }
}

extern "C" void kernel_launch(void* const* d_in, const int* in_sizes, int n_in,
                              void* d_out, int out_size, void* d_ws, size_t ws_size,
                              hipStream_t stream) {
    const float* input = (const float*)d_in[0];
    const float* beta  = (const float*)d_in[1];
    const int*   sel   = (const int*)d_in[2];
    float* out = (float*)d_out;
    float* ws  = (float*)d_ws;

    // 1) partial min/max over the selected slice
    k_minmax<<<RED_BLOCKS, RED_THREADS, 0, stream>>>(input, sel, ws);
    // 2) final reduce + softmax + flags + scalar scale output
    k_finish<<<1, RED_BLOCKS, 0, stream>>>(beta, sel, ws, out + NTOT);
    // 3) streaming copy / quant-mix
    k_main<<<4096, 256, 0, stream>>>(input, out, ws);
}

// Round 9
// 191.545 us; speedup vs baseline: 1.0010x; 1.0010x over previous
//
#include <hip/hip_runtime.h>

// Problem constants (from reference)
#define B_    32
#define C_    256
#define H_    56
#define W_    56
#define HW    (H_ * W_)          // 3136
#define HW4   (HW / 4)           // 784 f32x4 per channel plane
#define NSEL  8
#define NTOT  (B_ * C_ * HW)     // 25,690,112 elements
#define NTOT4 (NTOT / 4)         // 6,422,528 f32x4
#define NSELTOT4 (B_ * NSEL * HW4)  // 200,704 f32x4 in selected slice

#define RED_BLOCKS 256
#define TPB        256

// Native clang vector type: accepted by __builtin_nontemporal_store,
// same 16-byte layout/alignment as HIP float4.
typedef float f32x4 __attribute__((ext_vector_type(4)));

// ws layout (floats): [0..256) partial mins | [256..512) partial maxes
__global__ __launch_bounds__(TPB)
void k_minmax(const float* __restrict__ in, const int* __restrict__ sel,
              float* __restrict__ ws) {
    __shared__ float smn[TPB], smx[TPB];
    __shared__ int ssel[NSEL];
    if (threadIdx.x < NSEL) ssel[threadIdx.x] = sel[threadIdx.x];
    __syncthreads();

    float mn = INFINITY, mx = -INFINITY;
    const f32x4* in4 = reinterpret_cast<const f32x4*>(in);
    for (int i = blockIdx.x * TPB + threadIdx.x; i < NSELTOT4;
         i += RED_BLOCKS * TPB) {
        int pos = i % HW4;
        int t   = i / HW4;
        int j   = t % NSEL;
        int b   = t / NSEL;
        f32x4 v = in4[(b * C_ + ssel[j]) * HW4 + pos];
        mn = fminf(mn, fminf(fminf(v.x, v.y), fminf(v.z, v.w)));
        mx = fmaxf(mx, fmaxf(fmaxf(v.x, v.y), fmaxf(v.z, v.w)));
    }
    smn[threadIdx.x] = mn;
    smx[threadIdx.x] = mx;
    __syncthreads();
    for (int s = TPB / 2; s > 0; s >>= 1) {
        if (threadIdx.x < s) {
            smn[threadIdx.x] = fminf(smn[threadIdx.x], smn[threadIdx.x + s]);
            smx[threadIdx.x] = fmaxf(smx[threadIdx.x], smx[threadIdx.x + s]);
        }
        __syncthreads();
    }
    if (threadIdx.x == 0) {
        ws[blockIdx.x]              = smn[0];
        ws[RED_BLOCKS + blockIdx.x] = smx[0];
    }
}

__device__ __forceinline__ float qmix(float x, float mn,
                                      float sc2, float sc4, float sc8,
                                      float sw0, float sw1, float sw2) {
    float d = x - mn;
    // jnp.round == round-half-to-even == rintf (default rounding mode)
    float q2 = fminf(fmaxf(rintf(d / sc2), 0.0f), 3.0f);
    float q4 = fminf(fmaxf(rintf(d / sc4), 0.0f), 15.0f);
    float q8 = fminf(fmaxf(rintf(d / sc8), 0.0f), 255.0f);
    float o2 = q2 * sc2 + mn;
    float o4 = q4 * sc4 + mn;
    float o8 = q8 * sc8 + mn;
    return o2 * sw0 + o4 * sw1 + o8 * sw2;  // same left-to-right order as ref
}

// k_finish folded in: every block redundantly reduces the 256 partials
// (2 KB, L2-hot — kernel boundary guarantees visibility of ws), computes
// softmax + flags, then streams. No grid sync / atomics / cooperative
// launch needed.
__global__ __launch_bounds__(TPB)
void k_main2(const float* __restrict__ in, const float* __restrict__ beta,
             const int* __restrict__ sel, float* __restrict__ out,
             const float* __restrict__ ws) {
    __shared__ float smn[TPB], smx[TPB];
    __shared__ int flags[C_];
    const int tid = threadIdx.x;

    // final min/max reduce: TPB == RED_BLOCKS, one partial pair per thread
    smn[tid] = ws[tid];
    smx[tid] = ws[RED_BLOCKS + tid];
    __syncthreads();
    for (int s = TPB / 2; s > 0; s >>= 1) {
        if (tid < s) {
            smn[tid] = fminf(smn[tid], smn[tid + s]);
            smx[tid] = fmaxf(smx[tid], smx[tid + s]);
        }
        __syncthreads();
    }
    const float mnf = smn[0];
    const float mxf = smx[0];

    // flag table: TPB == C_ == 256, one channel per thread (sel is L2-hot)
    int f = 0;
    #pragma unroll
    for (int j = 0; j < NSEL; ++j) f |= (sel[j] == tid) ? 1 : 0;
    flags[tid] = f;
    __syncthreads();

    // softmax of beta — all threads redundantly, registers only
    const float b0 = beta[0], b1 = beta[1], b2 = beta[2];
    const float bm = fmaxf(b0, fmaxf(b1, b2));
    const float e0 = expf(b0 - bm), e1 = expf(b1 - bm), e2 = expf(b2 - bm);
    const float inv = 1.0f / (e0 + e1 + e2);
    const float sw0 = e0 * inv, sw1 = e1 * inv, sw2 = e2 * inv;

    const float range = mxf - mnf;
    const float sc2 = range / 3.0f;
    const float sc4 = range / 15.0f;
    const float sc8 = range / 255.0f;

    // returned scale = final loop iteration's (bit=8)
    if (blockIdx.x == 0 && tid == 0) out[NTOT] = sc8;

    // streaming copy / quant-mix over the full tensor
    const f32x4* in4 = reinterpret_cast<const f32x4*>(in);
    f32x4* out4 = reinterpret_cast<f32x4*>(out);
    for (int i = blockIdx.x * TPB + tid; i < NTOT4;
         i += gridDim.x * TPB) {
        f32x4 v = in4[i];
        int c = (i / HW4) % C_;  // f32x4 fully inside one channel plane
        if (flags[c]) {
            v.x = qmix(v.x, mnf, sc2, sc4, sc8, sw0, sw1, sw2);
            v.y = qmix(v.y, mnf, sc2, sc4, sc8, sw0, sw1, sw2);
            v.z = qmix(v.z, mnf, sc2, sc4, sc8, sw0, sw1, sw2);
            v.w = qmix(v.w, mnf, sc2, sc4, sc8, sw0, sw1, sw2);
        }
        // Streaming write, no reuse: non-temporal hint (coherent, safe).
        __builtin_nontemporal_store(v, &out4[i]);
    }
}

extern "C" void kernel_launch(void* const* d_in, const int* in_sizes, int n_in,
                              void* d_out, int out_size, void* d_ws, size_t ws_size,
                              hipStream_t stream) {
    const float* input = (const float*)d_in[0];
    const float* beta  = (const float*)d_in[1];
    const int*   sel   = (const int*)d_in[2];
    float* out = (float*)d_out;
    float* ws  = (float*)d_ws;

    // 1) partial min/max over the selected slice
    k_minmax<<<RED_BLOCKS, TPB, 0, stream>>>(input, sel, ws);
    // 2) redundant finish + streaming quant-mix (kernel boundary = sync)
    k_main2<<<4096, TPB, 0, stream>>>(input, beta, sel, out, ws);
}